// Round 13
// baseline (50.620 us; speedup 1.0000x reference)
//
#include <hip/hip_runtime.h>

#define B_ 128
#define S_ 512
#define H_ 1024
#define L_ 9
#define NB 512  // blocks: exactly 2 per CU

typedef float f32x4 __attribute__((ext_vector_type(4)));

// Position of the r-th (0-based) set bit of m. Caller guarantees popcount(m) > r.
__device__ __forceinline__ int select_bit(unsigned long long m, int r) {
    int pos = 0;
#pragma unroll
    for (int w = 32; w >= 1; w >>= 1) {
        unsigned long long lowmask = ((1ull << w) - 1ull);
        int c = __popcll(m & lowmask);
        if (r >= c) { r -= c; m >>= w; pos += w; }
    }
    return pos;
}

// Single fused kernel: per-block recompute of compaction state (counts ->
// prefix -> ballot-select), pad writes, and the R10 streaming GEMM core.
__global__ __launch_bounds__(256, 2) void fused_kernel(
    const float* __restrict__ seq, const float* __restrict__ Wm,
    const float* __restrict__ bias, const int* __restrict__ valid,
    float* __restrict__ out) {
    __shared__ __align__(16) float Wl[H_ * L_];  // 36,864 B
    __shared__ int cnt[256];
    __shared__ int offs[B_ + 1];
    __shared__ int srow[64], orow[64];

    const int tid = threadIdx.x;
    const int lane = tid & 63;
    const int wv = __builtin_amdgcn_readfirstlane(tid >> 6);
    const int hl = lane & 15;
    const int g = lane >> 4;

    // ---- W -> LDS (reused; stays in cache hierarchy) ----
    {
        const float4* Wg = (const float4*)Wm;
        float4* Wd = (float4*)Wl;
#pragma unroll
        for (int k = 0; k < 9; ++k) Wd[k * 256 + tid] = Wg[k * 256 + tid];
    }

    // ---- count phase: thread t counts batch (t>>1), half (t&1) ----
    {
        const int4* vp =
            (const int4*)(valid + (size_t)(tid >> 1) * S_ + (tid & 1) * 256);
        int c = 0;
#pragma unroll
        for (int k = 0; k < 64; ++k) {
            int4 v = vp[k];
            c += (v.x != 0) + (v.y != 0) + (v.z != 0) + (v.w != 0);
        }
        cnt[tid] = c;
    }
    __syncthreads();

    // ---- 128-wide exclusive prefix of per-batch counts -> offs ----
    if (tid < 64) {
        int s0 = cnt[2 * lane] + cnt[2 * lane + 1];
        int s1 = cnt[128 + 2 * lane] + cnt[128 + 2 * lane + 1];
#pragma unroll
        for (int d = 1; d < 64; d <<= 1) {
            int t0 = __shfl_up(s0, d, 64), t1 = __shfl_up(s1, d, 64);
            if (lane >= d) { s0 += t0; s1 += t1; }
        }
        int tot0 = __shfl(s0, 63, 64);
        offs[1 + lane] = s0;
        offs[65 + lane] = tot0 + s1;
        if (lane == 0) offs[0] = 0;
    }
    __syncthreads();

    const int total = offs[B_];

    // ---- pad rows: threads [64,192) write this block's pad slice ----
    // (concurrent with dense mapping below; touches no shared LDS state)
    if (tid >= 64 && tid < 192) {
        const int P = B_ * S_ - total;
        const int padchunk = (P + NB - 1) / NB;  // <= 128
        int pi = tid - 64;
        int p = blockIdx.x * padchunk + pi;
        if (pi < padchunk && p < P) {
            int lo = 0, hi = B_;
            while (hi - lo > 1) {
                int mid = (lo + hi) >> 1;
                if (mid * S_ - offs[mid] <= p) lo = mid; else hi = mid;
            }
            int nv = offs[lo + 1] - offs[lo];
            int j = nv + (p - (lo * S_ - offs[lo]));
            float pv[L_];
            float mx = bias[0];
#pragma unroll
            for (int l = 1; l < L_; ++l) mx = fmaxf(mx, bias[l]);
            float s = 0.f;
#pragma unroll
            for (int l = 0; l < L_; ++l) { pv[l] = expf(bias[l] - mx); s += pv[l]; }
            float inv = 1.f / s;
            float* op = out + ((size_t)lo * S_ + j) * L_;
#pragma unroll
            for (int l = 0; l < L_; ++l)
                __builtin_nontemporal_store(pv[l] * inv, op + l);
        }
    }

    const int chunk = (total + NB - 1) / NB;
    const int Gs = blockIdx.x * chunk;
    const int Ge = min(Gs + chunk, total);
    if (Gs >= Ge) return;  // block-uniform (pad threads already done)

    for (int t0 = Gs; t0 < Ge; t0 += 64) {
        // ---- dense mapping: binary search + ballot-select (wave 0) ----
        if (tid < 64) {
            const int G = t0 + lane;
            const bool act = G < Ge;
            int bt = 0, jt = 0;
            if (act) {
                int lo = 0, hi = B_;
                while (hi - lo > 1) {
                    int mid = (lo + hi) >> 1;
                    if (offs[mid] <= G) lo = mid; else hi = mid;
                }
                bt = lo;
                jt = G - offs[lo];
            }
            srow[lane] = -1;
            orow[lane] = act ? bt * S_ + jt : 0;
            int lastA = Ge - 1 - t0;
            if (lastA > 63) lastA = 63;
            const int blo = __shfl(bt, 0);
            const int bhi = __shfl(bt, lastA);
            for (int bb = blo; bb <= bhi; ++bb) {  // <=3 batches per tile
                const int* vrow = valid + (size_t)bb * S_;
                int base = 0;
#pragma unroll
                for (int c = 0; c < 8; ++c) {
                    int vv = vrow[c * 64 + lane];
                    unsigned long long m = __ballot(vv != 0);
                    int pc = __popcll(m);
                    if (act && bt == bb && jt >= base && jt < base + pc)
                        srow[lane] = bb * S_ + c * 64 + select_bit(m, jt - base);
                    base += pc;
                }
            }
        }
        __syncthreads();

        // ---- R10 streaming core: 4 waves x 16 rows, hl spans h ----
        const float* rp[4];
#pragma unroll
        for (int s = 0; s < 4; ++s) {
            int sa = srow[16 * wv + 4 * s + g];
            rp[s] = seq + (size_t)(sa < 0 ? 0 : sa) * H_ + 4 * hl;
        }

        float acc[4][L_];
#pragma unroll
        for (int s = 0; s < 4; ++s)
#pragma unroll
            for (int l = 0; l < L_; ++l) acc[s][l] = 0.f;

#pragma unroll 2
        for (int it = 0; it < 16; ++it) {
            f32x4 xv0 = __builtin_nontemporal_load((const f32x4*)(rp[0] + 64 * it));
            f32x4 xv1 = __builtin_nontemporal_load((const f32x4*)(rp[1] + 64 * it));
            f32x4 xv2 = __builtin_nontemporal_load((const f32x4*)(rp[2] + 64 * it));
            f32x4 xv3 = __builtin_nontemporal_load((const f32x4*)(rp[3] + 64 * it));
            const float* wf = Wl + 36 * hl + 576 * it;
            float wr[36];
#pragma unroll
            for (int j = 0; j < 9; ++j)
                *(float4*)&wr[4 * j] = *(const float4*)(wf + 4 * j);
            float xk0[4] = {xv0[0], xv0[1], xv0[2], xv0[3]};
            float xk1[4] = {xv1[0], xv1[1], xv1[2], xv1[3]};
            float xk2[4] = {xv2[0], xv2[1], xv2[2], xv2[3]};
            float xk3[4] = {xv3[0], xv3[1], xv3[2], xv3[3]};
#pragma unroll
            for (int k = 0; k < 4; ++k)
#pragma unroll
                for (int l = 0; l < L_; ++l) {
                    float w = wr[9 * k + l];
                    acc[0][l] = fmaf(xk0[k], w, acc[0][l]);
                    acc[1][l] = fmaf(xk1[k], w, acc[1][l]);
                    acc[2][l] = fmaf(xk2[k], w, acc[2][l]);
                    acc[3][l] = fmaf(xk3[k], w, acc[3][l]);
                }
        }

        // 16-wide hl-butterfly (once per tile)
#pragma unroll
        for (int m = 1; m < 16; m <<= 1)
#pragma unroll
            for (int s = 0; s < 4; ++s)
#pragma unroll
                for (int l = 0; l < L_; ++l)
                    acc[s][l] += __shfl_xor(acc[s][l], m);

        // lanes hl<4 write row 16*wv + 4*hl + g
        if (hl < 4) {
            float v[L_];
#pragma unroll
            for (int s = 0; s < 4; ++s)
                if (hl == s) {
#pragma unroll
                    for (int l = 0; l < L_; ++l) v[l] = acc[s][l];
                }
            int rw = 16 * wv + 4 * hl + g;
            if (srow[rw] >= 0) {
#pragma unroll
                for (int l = 0; l < L_; ++l) v[l] += bias[l];
                float mx = v[0];
#pragma unroll
                for (int l = 1; l < L_; ++l) mx = fmaxf(mx, v[l]);
                float s = 0.f;
#pragma unroll
                for (int l = 0; l < L_; ++l) {
                    v[l] = expf(v[l] - mx);
                    s += v[l];
                }
                float inv = 1.f / s;
                float* op = out + (size_t)orow[rw] * L_;
#pragma unroll
                for (int l = 0; l < L_; ++l)
                    __builtin_nontemporal_store(v[l] * inv, op + l);
            }
        }
        __syncthreads();  // protect srow/orow before next tile overwrites
    }
}

extern "C" void kernel_launch(void* const* d_in, const int* in_sizes, int n_in,
                              void* d_out, int out_size, void* d_ws, size_t ws_size,
                              hipStream_t stream) {
    const float* seq = (const float*)d_in[0];   // [B,S,H] f32
    const float* W = (const float*)d_in[1];     // [H,L] f32
    const float* bias = (const float*)d_in[2];  // [L] f32
    const int* valid = (const int*)d_in[3];     // [B,S] i32
    float* out = (float*)d_out;                 // [B,S,L] f32

    fused_kernel<<<dim3(NB), dim3(256), 0, stream>>>(seq, W, bias, valid, out);
}

// Round 14
// 34.367 us; speedup vs baseline: 1.4729x; 1.4729x over previous
//
#include <hip/hip_runtime.h>

#define B_ 128
#define S_ 512
#define H_ 1024
#define L_ 9
#define NB 512  // gemm blocks: exactly 2 per CU, equal static chunks

// ---- Kernel A: compaction map + pad-row outputs (wave-parallel) ----
__global__ __launch_bounds__(256) void prep_kernel(
    const int* __restrict__ valid, const float* __restrict__ bias,
    float* __restrict__ out, int* __restrict__ ws_src, int* __restrict__ ws_nv) {
    __shared__ int cnt[8];
    const int lane = threadIdx.x & 63;
    const int wv = threadIdx.x >> 6;
    const int b = blockIdx.x;
    const int* vrow = valid + (size_t)b * S_;

    int v0 = vrow[128 * wv + lane];
    int v1 = vrow[128 * wv + 64 + lane];
    unsigned long long m0 = __ballot(v0 != 0);
    unsigned long long m1 = __ballot(v1 != 0);
    if (lane == 0) { cnt[2 * wv] = __popcll(m0); cnt[2 * wv + 1] = __popcll(m1); }
    __syncthreads();

    int base0 = 0, total = 0;
#pragma unroll
    for (int k = 0; k < 8; ++k) {
        if (k < 2 * wv) base0 += cnt[k];
        total += cnt[k];
    }
    int base1 = base0 + cnt[2 * wv];
    if (v0) ws_src[b * S_ + base0 + __popcll(m0 & ((1ull << lane) - 1ull))] =
        128 * wv + lane;
    if (v1) ws_src[b * S_ + base1 + __popcll(m1 & ((1ull << lane) - 1ull))] =
        128 * wv + 64 + lane;
    if (threadIdx.x == 0) ws_nv[b] = total;

    // pad rows [total, 512): softmax(bias)
    float pv[L_];
    float mx = bias[0];
#pragma unroll
    for (int l = 1; l < L_; ++l) mx = fmaxf(mx, bias[l]);
    float s = 0.f;
#pragma unroll
    for (int l = 0; l < L_; ++l) { pv[l] = expf(bias[l] - mx); s += pv[l]; }
    float inv = 1.f / s;
#pragma unroll
    for (int l = 0; l < L_; ++l) pv[l] *= inv;
    for (int j = total + threadIdx.x; j < S_; j += 256) {
        float* op = out + ((size_t)b * S_ + j) * L_;
#pragma unroll
        for (int l = 0; l < L_; ++l) op[l] = pv[l];
    }
}

// ---- Kernel B: equal-chunk GEMM (best-measured config, R10/R12) ----
// 512 blocks x 256 thr, each owns chunk=ceil(total/512) contiguous dense rows,
// processed in 64-row tiles (4 waves x 16 rows; hl=lane&15 spans h, g=lane>>4
// picks row, 4 row-slots/lane). W (36KB) in LDS once; 9x broadcast
// ds_read_b128/iter; 16-wide butterfly once per tile.
__global__ __launch_bounds__(256, 2) void gemm_kernel(
    const float* __restrict__ seq, const float* __restrict__ Wm,
    const float* __restrict__ bias, const int* __restrict__ ws_src,
    const int* __restrict__ ws_nv, float* __restrict__ out) {
    __shared__ __align__(16) float Wl[H_ * L_];  // 36,864 B
    __shared__ int offs[B_ + 1];
    __shared__ int srow[64], orow[64];

    const int tid = threadIdx.x;
    const int lane = tid & 63;
    const int wv = __builtin_amdgcn_readfirstlane(tid >> 6);
    const int hl = lane & 15;
    const int g = lane >> 4;

    if (tid < 64) {  // 128-wide exclusive prefix of ws_nv
        int s0 = ws_nv[lane], s1 = ws_nv[64 + lane];
#pragma unroll
        for (int d = 1; d < 64; d <<= 1) {
            int t0 = __shfl_up(s0, d, 64), t1 = __shfl_up(s1, d, 64);
            if (lane >= d) { s0 += t0; s1 += t1; }
        }
        int tot0 = __shfl(s0, 63, 64);
        offs[1 + lane] = s0;
        offs[65 + lane] = tot0 + s1;
        if (lane == 0) offs[0] = 0;
    }
    {  // cooperative W -> LDS
        const float4* Wg = (const float4*)Wm;
        float4* Wd = (float4*)Wl;
#pragma unroll
        for (int k = 0; k < 9; ++k) Wd[k * 256 + tid] = Wg[k * 256 + tid];
    }
    __syncthreads();

    const int total = offs[B_];
    const int chunk = (total + NB - 1) / NB;
    const int Gs = blockIdx.x * chunk;
    const int Ge = min(Gs + chunk, total);
    if (Gs >= Ge) return;  // block-uniform

    for (int t0 = Gs; t0 < Ge; t0 += 64) {
        // map this tile's rows (thread t -> tile row t)
        if (tid < 64) {
            int G = t0 + tid;
            int sa = -1, o = 0;
            if (G < Ge) {
                int lo = 0, hi = B_;
                while (hi - lo > 1) {
                    int mid = (lo + hi) >> 1;
                    if (offs[mid] <= G) lo = mid; else hi = mid;
                }
                int j = G - offs[lo];
                o = lo * S_ + j;
                sa = lo * S_ + ws_src[o];
            }
            srow[tid] = sa;  // -1 = outside this block's range
            orow[tid] = o;
        }
        __syncthreads();

        const float* rp[4];
#pragma unroll
        for (int s = 0; s < 4; ++s) {
            int sa = srow[16 * wv + 4 * s + g];
            rp[s] = seq + (size_t)(sa < 0 ? 0 : sa) * H_ + 4 * hl;
        }

        float acc[4][L_];
#pragma unroll
        for (int s = 0; s < 4; ++s)
#pragma unroll
            for (int l = 0; l < L_; ++l) acc[s][l] = 0.f;

#pragma unroll 2
        for (int it = 0; it < 16; ++it) {
            float4 xv0 = *(const float4*)(rp[0] + 64 * it);
            float4 xv1 = *(const float4*)(rp[1] + 64 * it);
            float4 xv2 = *(const float4*)(rp[2] + 64 * it);
            float4 xv3 = *(const float4*)(rp[3] + 64 * it);
            const float* wf = Wl + 36 * hl + 576 * it;
            float wr[36];
#pragma unroll
            for (int j = 0; j < 9; ++j)
                *(float4*)&wr[4 * j] = *(const float4*)(wf + 4 * j);
            float xk0[4] = {xv0.x, xv0.y, xv0.z, xv0.w};
            float xk1[4] = {xv1.x, xv1.y, xv1.z, xv1.w};
            float xk2[4] = {xv2.x, xv2.y, xv2.z, xv2.w};
            float xk3[4] = {xv3.x, xv3.y, xv3.z, xv3.w};
#pragma unroll
            for (int k = 0; k < 4; ++k)
#pragma unroll
                for (int l = 0; l < L_; ++l) {
                    float w = wr[9 * k + l];
                    acc[0][l] = fmaf(xk0[k], w, acc[0][l]);
                    acc[1][l] = fmaf(xk1[k], w, acc[1][l]);
                    acc[2][l] = fmaf(xk2[k], w, acc[2][l]);
                    acc[3][l] = fmaf(xk3[k], w, acc[3][l]);
                }
        }

        // 16-wide hl-butterfly (once per tile)
#pragma unroll
        for (int m = 1; m < 16; m <<= 1)
#pragma unroll
            for (int s = 0; s < 4; ++s)
#pragma unroll
                for (int l = 0; l < L_; ++l)
                    acc[s][l] += __shfl_xor(acc[s][l], m);

        // lanes hl<4 write row 16*wv + 4*hl + g
        if (hl < 4) {
            float v[L_];
#pragma unroll
            for (int s = 0; s < 4; ++s)
                if (hl == s) {
#pragma unroll
                    for (int l = 0; l < L_; ++l) v[l] = acc[s][l];
                }
            int rw = 16 * wv + 4 * hl + g;
            if (srow[rw] >= 0) {
#pragma unroll
                for (int l = 0; l < L_; ++l) v[l] += bias[l];
                float mx = v[0];
#pragma unroll
                for (int l = 1; l < L_; ++l) mx = fmaxf(mx, v[l]);
                float s = 0.f;
#pragma unroll
                for (int l = 0; l < L_; ++l) {
                    v[l] = expf(v[l] - mx);
                    s += v[l];
                }
                float inv = 1.f / s;
                float* op = out + (size_t)orow[rw] * L_;
#pragma unroll
                for (int l = 0; l < L_; ++l) op[l] = v[l] * inv;
            }
        }
        __syncthreads();  // protect srow/orow before next tile overwrites
    }
}

extern "C" void kernel_launch(void* const* d_in, const int* in_sizes, int n_in,
                              void* d_out, int out_size, void* d_ws, size_t ws_size,
                              hipStream_t stream) {
    const float* seq = (const float*)d_in[0];   // [B,S,H] f32
    const float* W = (const float*)d_in[1];     // [H,L] f32
    const float* bias = (const float*)d_in[2];  // [L] f32
    const int* valid = (const int*)d_in[3];     // [B,S] i32
    float* out = (float*)d_out;                 // [B,S,L] f32

    int* ws_src = (int*)d_ws;        // [128*512] within-batch source indices
    int* ws_nv = ws_src + B_ * S_;   // [128] valid counts

    prep_kernel<<<dim3(B_), dim3(256), 0, stream>>>(valid, bias, out, ws_src, ws_nv);
    gemm_kernel<<<dim3(NB), dim3(256), 0, stream>>>(seq, W, bias, ws_src, ws_nv,
                                                    out);
}